// Round 1
// baseline (139.125 us; speedup 1.0000x reference)
//
#include <hip/hip_runtime.h>

#define EPS_DEF 1.1920928955078125e-07f

// Problem geometry (fixed by reference setup_inputs)
//   x: (32,512,12,24)    -> 16384 blocks of 288
//   y: (32,512,12,16)    -> 16384 blocks of 192
//   z: (32,512,12,16,24) -> 16384 blocks of 4608 (192 rows of 24)

__launch_bounds__(256)
__global__ void fused_rms_kernel(const float* __restrict__ x,
                                 const float* __restrict__ y,
                                 const float* __restrict__ z,
                                 const float* __restrict__ w0,
                                 const float* __restrict__ w1,
                                 const float* __restrict__ w2,
                                 const float* __restrict__ w3,
                                 const float* __restrict__ w4,
                                 const float* __restrict__ w5,
                                 float* __restrict__ ox,
                                 float* __restrict__ oy,
                                 float* __restrict__ oz)
{
    __shared__ float zs[192 * 25];   // z block, rows padded 24->25
    __shared__ float xs[12 * 25];    // x block
    __shared__ float ys[12 * 17];    // y block, rows padded 16->17
    __shared__ float w0s[24], w2s[24], w3s[24], w5s[24];
    __shared__ float w1s[192], w4s[192];
    __shared__ float wpart[4][4];    // per-wave partial sums (Sz, Sx, Sy0, Sy1)
    __shared__ float az[192], ax[12], ay[12];

    const int tid = threadIdx.x;
    const int bid = blockIdx.x;

    // ---- stage weights ----
    if (tid < 24) {
        w0s[tid] = w0[tid];
        w2s[tid] = w2[tid];
        w3s[tid] = w3[tid];
        w5s[tid] = w5[tid];
    }
    if (tid < 192) {
        w1s[tid] = w1[tid];
        w4s[tid] = w4[tid];
    }

    // ---- stage data blocks into LDS (coalesced float4 loads) ----
    const float4* zp = (const float4*)(z + (size_t)bid * 4608);
    const float4* xp = (const float4*)(x + (size_t)bid * 288);
    const float4* yp = (const float4*)(y + (size_t)bid * 192);

    for (int v = tid; v < 1152; v += 256) {   // 4608/4; 24%4==0 so a float4 never crosses a row
        float4 q = zp[v];
        int k = v * 4, r = k / 24, c = k - r * 24;
        float* d = &zs[r * 25 + c];
        d[0] = q.x; d[1] = q.y; d[2] = q.z; d[3] = q.w;
    }
    if (tid < 72) {                            // 288/4
        float4 q = xp[tid];
        int k = tid * 4, r = k / 24, c = k - r * 24;
        float* d = &xs[r * 25 + c];
        d[0] = q.x; d[1] = q.y; d[2] = q.z; d[3] = q.w;
    }
    if (tid < 48) {                            // 192/4
        float4 q = yp[tid];
        int k = tid * 4, r = k / 16, c = k - r * 16;
        float* d = &ys[r * 17 + c];
        d[0] = q.x; d[1] = q.y; d[2] = q.z; d[3] = q.w;
    }
    __syncthreads();

    // ---- per-row reductions: tids 0..191 = z rows, 192..203 = x rows, 204..215 = y rows ----
    float p0 = 0.f, p1 = 0.f, p2 = 0.f, p3 = 0.f;   // block-sum partials
    float r1 = 0.f, sw = 0.f;                        // per-row saved state

    if (tid < 192) {
        const float* row = &zs[tid * 25];
        float s0 = 0.f, s = 0.f;
        #pragma unroll
        for (int j = 0; j < 24; ++j) {
            float v = row[j];
            float vw = v * w2s[j];
            s0 += v * v;
            s += vw * vw;
        }
        r1 = rsqrtf(s0 * (1.f / 24.f) + EPS_DEF);
        sw = s;
        p0 = r1 * r1 * s;
    } else if (tid < 204) {
        int i = tid - 192;
        const float* row = &xs[i * 25];
        float s0 = 0.f, s = 0.f;
        #pragma unroll
        for (int j = 0; j < 24; ++j) {
            float v = row[j];
            float vw = v * w0s[j];
            s0 += v * v;
            s += vw * vw;
        }
        r1 = rsqrtf(s0 * (1.f / 24.f) + EPS_DEF);
        sw = s;
        p1 = r1 * r1 * s;
    } else if (tid < 216) {
        int i = tid - 204;
        const float* row = &ys[i * 17];
        const float* w1r = &w1s[i * 16];
        float s0 = 0.f, s = 0.f;
        #pragma unroll
        for (int j = 0; j < 16; ++j) {
            float v = row[j];
            float vw = v * w1r[j];
            s0 += v * v;
            s += vw * vw;
        }
        r1 = rsqrtf(s0 * (1.f / 16.f) + 1e-3f);   // y step-1 eps = 0.001
        sw = s;
        p2 = r1 * r1 * s0;   // for step-2 mean (unweighted)
        p3 = r1 * r1 * s;    // for step-3 mean (w1-weighted)
    }

    // ---- block reduction of the 4 partials (wave shuffle + LDS combine) ----
    #pragma unroll
    for (int d = 32; d > 0; d >>= 1) {
        p0 += __shfl_down(p0, d, 64);
        p1 += __shfl_down(p1, d, 64);
        p2 += __shfl_down(p2, d, 64);
        p3 += __shfl_down(p3, d, 64);
    }
    const int wave = tid >> 6;
    if ((tid & 63) == 0) {
        wpart[wave][0] = p0; wpart[wave][1] = p1;
        wpart[wave][2] = p2; wpart[wave][3] = p3;
    }
    __syncthreads();

    const float Sz  = wpart[0][0] + wpart[1][0] + wpart[2][0] + wpart[3][0];
    const float Sx  = wpart[0][1] + wpart[1][1] + wpart[2][1] + wpart[3][1];
    const float Sy0 = wpart[0][2] + wpart[1][2] + wpart[2][2] + wpart[3][2];
    const float Sy1 = wpart[0][3] + wpart[1][3] + wpart[2][3] + wpart[3][3];

    const float cZ  = rsqrtf(Sz  * (1.f / 4608.f) + 0.01f);    // z step-2 eps = 0.01
    const float cX  = rsqrtf(Sx  * (1.f / 288.f)  + EPS_DEF);
    const float c2y = rsqrtf(Sy0 * (1.f / 192.f)  + EPS_DEF);
    const float c3y = rsqrtf(c2y * c2y * Sy1 * (1.f / 192.f) + EPS_DEF);

    // ---- finalize per-row combined scales ----
    if (tid < 192) {
        float r3 = rsqrtf(cZ * cZ * r1 * r1 * sw * (1.f / 24.f) + EPS_DEF);
        az[tid] = r1 * cZ * r3;
    } else if (tid < 204) {
        float r3 = rsqrtf(cX * cX * r1 * r1 * sw * (1.f / 24.f) + EPS_DEF);
        ax[tid - 192] = r1 * cX * r3;
    } else if (tid < 216) {
        ay[tid - 204] = r1 * c2y * c3y;
    }
    __syncthreads();

    // ---- write outputs (coalesced float4, fused scales) ----
    float4* ozp = (float4*)(oz + (size_t)bid * 4608);
    for (int v = tid; v < 1152; v += 256) {
        int k = v * 4, r = k / 24, c = k - r * 24;
        const float* s = &zs[r * 25 + c];
        float a = az[r];
        float4 q;
        q.x = s[0] * a * w2s[c + 0] * w5s[c + 0];
        q.y = s[1] * a * w2s[c + 1] * w5s[c + 1];
        q.z = s[2] * a * w2s[c + 2] * w5s[c + 2];
        q.w = s[3] * a * w2s[c + 3] * w5s[c + 3];
        ozp[v] = q;
    }
    if (tid < 72) {
        int k = tid * 4, r = k / 24, c = k - r * 24;
        const float* s = &xs[r * 25 + c];
        float a = ax[r];
        float4 q;
        q.x = s[0] * a * w0s[c + 0] * w3s[c + 0];
        q.y = s[1] * a * w0s[c + 1] * w3s[c + 1];
        q.z = s[2] * a * w0s[c + 2] * w3s[c + 2];
        q.w = s[3] * a * w0s[c + 3] * w3s[c + 3];
        ((float4*)(ox + (size_t)bid * 288))[tid] = q;
    }
    if (tid < 48) {
        int k = tid * 4, r = k / 16, c = k - r * 16;
        const float* s = &ys[r * 17 + c];
        float a = ay[r];
        float4 q;
        q.x = s[0] * a * w1s[k + 0] * w4s[k + 0];
        q.y = s[1] * a * w1s[k + 1] * w4s[k + 1];
        q.z = s[2] * a * w1s[k + 2] * w4s[k + 2];
        q.w = s[3] * a * w1s[k + 3] * w4s[k + 3];
        ((float4*)(oy + (size_t)bid * 192))[tid] = q;
    }
}

extern "C" void kernel_launch(void* const* d_in, const int* in_sizes, int n_in,
                              void* d_out, int out_size, void* d_ws, size_t ws_size,
                              hipStream_t stream) {
    const float* x  = (const float*)d_in[0];
    const float* y  = (const float*)d_in[1];
    const float* z  = (const float*)d_in[2];
    const float* w0 = (const float*)d_in[3];
    const float* w1 = (const float*)d_in[4];
    const float* w2 = (const float*)d_in[5];
    const float* w3 = (const float*)d_in[6];
    const float* w4 = (const float*)d_in[7];
    const float* w5 = (const float*)d_in[8];

    float* out = (float*)d_out;
    const size_t NX = (size_t)32 * 512 * 12 * 24;   // 4718592
    const size_t NY = (size_t)32 * 512 * 12 * 16;   // 3145728
    float* ox = out;
    float* oy = out + NX;
    float* oz = out + NX + NY;

    const int nblk = 32 * 512;   // 16384
    hipLaunchKernelGGL(fused_rms_kernel, dim3(nblk), dim3(256), 0, stream,
                       x, y, z, w0, w1, w2, w3, w4, w5, ox, oy, oz);
}